// Round 2
// baseline (5794.381 us; speedup 1.0000x reference)
//
#include <hip/hip_runtime.h>
#include <hip/hip_bf16.h>

// GCN-VAE encoder: mu = S(xW_mu)+b_mu, logstd = S(xW_ls)+b_ls
// S = D^-1/2 (A+I) D^-1/2  (in-degree by dst, self-loops included)
//
// Pipeline (all on `stream`):
//  1. k_detect   : decide whether edge_index is int64 or int32 (data-driven)
//  2. k_initdeg  : deg[i] = 1.0 (self-loop)
//  3. k_decode   : canonicalize src/dst into int32 arrays in ws + deg[dst] += 1
//  4. k_dinv     : dinv = rsqrt(deg) in place
//  5. k_gemm     : h[N][128] = x @ [W_mu | W_ls]   (fp32 vector FMA, LDS tiled)
//  6. k_selfinit : out = b + h * dinv^2            (initializes poisoned d_out)
//  7. k_edges    : out[dst] += h[src] * dinv[src]*dinv[dst]  (f32 atomics)

#define IN_C 256
#define HC   128   // concatenated output channels (64 mu + 64 ls)
#define OC   64

// ---------------------------------------------------------------- detect
__global__ void k_detect(const void* ei, int n_scan, long long nn, int* flag) {
    __shared__ int bad;
    if (threadIdx.x == 0) bad = 0;
    __syncthreads();
    const long long* p = (const long long*)ei;
    for (int i = threadIdx.x; i < n_scan; i += blockDim.x) {
        long long v = p[i];
        if (v < 0 || v >= nn) bad = 1;   // benign race
    }
    __syncthreads();
    if (threadIdx.x == 0) *flag = bad;   // 1 => data is int32, 0 => int64
}

// ---------------------------------------------------------------- degree init
__global__ __launch_bounds__(256) void k_initdeg(float* deg, int n) {
    int i = blockIdx.x * 256 + threadIdx.x;
    if (i < n) deg[i] = 1.0f;            // self-loop
}

// ---------------------------------------------------------------- decode + count
__global__ __launch_bounds__(256) void k_decode(const void* ei, int* src32, int* dst32,
                                                float* deg, int E, const int* flag) {
    int e = blockIdx.x * 256 + threadIdx.x;
    if (e >= E) return;
    int s, d;
    if (*flag) {
        const int* p = (const int*)ei;
        s = p[e];
        d = p[(size_t)E + e];
    } else {
        const long long* p = (const long long*)ei;
        s = (int)p[e];
        d = (int)p[(size_t)E + e];
    }
    src32[e] = s;
    dst32[e] = d;
    atomicAdd(&deg[d], 1.0f);
}

__global__ __launch_bounds__(256) void k_dinv(float* deg, int n) {
    int i = blockIdx.x * 256 + threadIdx.x;
    if (i < n) deg[i] = rsqrtf(deg[i]);  // deg >= 1 always
}

// ---------------------------------------------------------------- GEMM
// h[N][128] = x[N][256] @ [W_mu | W_ls][256][128]
// Block: 256 threads, tile 64 rows x 128 ch, thread-tile 4 rows x 8 ch.
#define BR 64
#define KC 32
__global__ __launch_bounds__(256) void k_gemm(const float* __restrict__ x,
                                              const float* __restrict__ Wmu,
                                              const float* __restrict__ Wls,
                                              float* __restrict__ hout, int nrows) {
    __shared__ float xs[BR][KC + 4];     // +4 pad keeps 16B alignment, breaks stride
    __shared__ float wsm[KC][HC];
    const int tid  = threadIdx.x;
    const int trow = tid >> 4;           // 0..15
    const int tcol = tid & 15;           // 0..15
    const int r0   = trow * 4;
    const int c0   = tcol * 4;           // channels c0..c0+3 and c0+64..c0+67
    const size_t rowbase = (size_t)blockIdx.x * BR;

    float acc[4][8];
    #pragma unroll
    for (int i = 0; i < 4; ++i)
        #pragma unroll
        for (int j = 0; j < 8; ++j) acc[i][j] = 0.0f;

    for (int kc = 0; kc < IN_C; kc += KC) {
        __syncthreads();
        // stage x tile: 64 rows x 32 k  (each thread 2 float4s, coalesced)
        {
            int lr = tid >> 3, lk = (tid & 7) * 4;
            #pragma unroll
            for (int half = 0; half < 2; ++half) {
                size_t gr = rowbase + lr + half * 32;
                float4 v = make_float4(0.f, 0.f, 0.f, 0.f);
                if (gr < (size_t)nrows)
                    v = *(const float4*)(x + gr * IN_C + kc + lk);
                *(float4*)&xs[lr + half * 32][lk] = v;
            }
        }
        // stage W chunk: 32 k x 128 ch (each thread 4 float4s)
        #pragma unroll
        for (int i = 0; i < 4; ++i) {
            int q  = tid + 256 * i;          // float4 index 0..1023
            int k  = q >> 5;                 // 32 float4 per k-row
            int cq = (q & 31) * 4;
            const float* srcw = (cq < OC) ? (Wmu + (size_t)(kc + k) * OC + cq)
                                          : (Wls + (size_t)(kc + k) * OC + (cq - OC));
            *(float4*)&wsm[k][cq] = *(const float4*)srcw;
        }
        __syncthreads();

        #pragma unroll 8
        for (int k = 0; k < KC; ++k) {
            float4 w0 = *(const float4*)&wsm[k][c0];
            float4 w1 = *(const float4*)&wsm[k][c0 + OC];
            float xv[4];
            #pragma unroll
            for (int i = 0; i < 4; ++i) xv[i] = xs[r0 + i][k];
            #pragma unroll
            for (int i = 0; i < 4; ++i) {
                acc[i][0] += xv[i] * w0.x; acc[i][1] += xv[i] * w0.y;
                acc[i][2] += xv[i] * w0.z; acc[i][3] += xv[i] * w0.w;
                acc[i][4] += xv[i] * w1.x; acc[i][5] += xv[i] * w1.y;
                acc[i][6] += xv[i] * w1.z; acc[i][7] += xv[i] * w1.w;
            }
        }
    }
    #pragma unroll
    for (int i = 0; i < 4; ++i) {
        size_t gr = rowbase + r0 + i;
        if (gr < (size_t)nrows) {
            *(float4*)(hout + gr * HC + c0)      = make_float4(acc[i][0], acc[i][1], acc[i][2], acc[i][3]);
            *(float4*)(hout + gr * HC + OC + c0) = make_float4(acc[i][4], acc[i][5], acc[i][6], acc[i][7]);
        }
    }
}

// ---------------------------------------------------------------- self-loop init
// out_mu[i] = b_mu + h_mu[i]*dinv[i]^2 ; same for ls.  16 threads per node.
__global__ __launch_bounds__(256) void k_selfinit(const float* __restrict__ h,
                                                  const float* __restrict__ dinv,
                                                  const float* __restrict__ bmu,
                                                  const float* __restrict__ bls,
                                                  float* __restrict__ out_mu,
                                                  float* __restrict__ out_ls, int n) {
    int t = blockIdx.x * 256 + threadIdx.x;
    int i = t >> 4;
    int j = t & 15;
    if (i >= n) return;
    float w = dinv[i] * dinv[i];
    const float* hb = h + (size_t)i * HC + j * 4;
    float4 h0 = *(const float4*)hb;
    float4 h1 = *(const float4*)(hb + OC);
    float4 b0 = *(const float4*)(bmu + j * 4);
    float4 b1 = *(const float4*)(bls + j * 4);
    float4 o0 = make_float4(b0.x + h0.x * w, b0.y + h0.y * w, b0.z + h0.z * w, b0.w + h0.w * w);
    float4 o1 = make_float4(b1.x + h1.x * w, b1.y + h1.y * w, b1.z + h1.z * w, b1.w + h1.w * w);
    *(float4*)(out_mu + (size_t)i * OC + j * 4) = o0;
    *(float4*)(out_ls + (size_t)i * OC + j * 4) = o1;
}

// ---------------------------------------------------------------- edge scatter
// 16 threads per edge; each handles one float4 of mu and one of ls.
__global__ __launch_bounds__(256) void k_edges(const int* __restrict__ src32,
                                               const int* __restrict__ dst32,
                                               const float* __restrict__ dinv,
                                               const float* __restrict__ h,
                                               float* __restrict__ out_mu,
                                               float* __restrict__ out_ls, int E) {
    long long tid = (long long)blockIdx.x * 256 + threadIdx.x;
    int e = (int)(tid >> 4);
    if (e >= E) return;
    int j = (int)(tid & 15);
    int s = src32[e];
    int d = dst32[e];
    float nrm = dinv[s] * dinv[d];
    const float* hb = h + (size_t)s * HC + j * 4;
    float4 h0 = *(const float4*)hb;
    float4 h1 = *(const float4*)(hb + OC);
    float* om = out_mu + (size_t)d * OC + j * 4;
    float* ol = out_ls + (size_t)d * OC + j * 4;
    atomicAdd(om + 0, h0.x * nrm);
    atomicAdd(om + 1, h0.y * nrm);
    atomicAdd(om + 2, h0.z * nrm);
    atomicAdd(om + 3, h0.w * nrm);
    atomicAdd(ol + 0, h1.x * nrm);
    atomicAdd(ol + 1, h1.y * nrm);
    atomicAdd(ol + 2, h1.z * nrm);
    atomicAdd(ol + 3, h1.w * nrm);
}

// ---------------------------------------------------------------- launch
extern "C" void kernel_launch(void* const* d_in, const int* in_sizes, int n_in,
                              void* d_out, int out_size, void* d_ws, size_t ws_size,
                              hipStream_t stream) {
    const float* x   = (const float*)d_in[0];
    const void*  ei  = d_in[1];
    const float* Wmu = (const float*)d_in[2];
    const float* bmu = (const float*)d_in[3];
    const float* Wls = (const float*)d_in[4];
    const float* bls = (const float*)d_in[5];

    const int N = in_sizes[0] / IN_C;
    const int E = in_sizes[1] / 2;

    float* out_mu = (float*)d_out;
    float* out_ls = (float*)d_out + (size_t)N * OC;

    // workspace layout (256B aligned)
    char* w = (char*)d_ws;
    auto align256 = [](size_t v) { return (v + 255) & ~(size_t)255; };
    int*   flag  = (int*)w;                    size_t off = 256;
    float* deg   = (float*)(w + off);          off += align256((size_t)N * 4);   // becomes dinv
    float* h     = (float*)(w + off);          off += align256((size_t)N * HC * 4);
    int*   src32 = (int*)(w + off);            off += align256((size_t)E * 4);
    int*   dst32 = (int*)(w + off);            off += align256((size_t)E * 4);

    int n_scan = E < 4096 ? E : 4096;
    hipLaunchKernelGGL(k_detect, dim3(1), dim3(256), 0, stream, ei, n_scan, (long long)N, flag);

    int gN = (N + 255) / 256;
    hipLaunchKernelGGL(k_initdeg, dim3(gN), dim3(256), 0, stream, deg, N);

    int gE = (E + 255) / 256;
    hipLaunchKernelGGL(k_decode, dim3(gE), dim3(256), 0, stream, ei, src32, dst32, deg, E, flag);

    hipLaunchKernelGGL(k_dinv, dim3(gN), dim3(256), 0, stream, deg, N);

    int gG = (N + BR - 1) / BR;
    hipLaunchKernelGGL(k_gemm, dim3(gG), dim3(256), 0, stream, x, Wmu, Wls, h, N);

    int gS = ((size_t)N * 16 + 255) / 256;
    hipLaunchKernelGGL(k_selfinit, dim3(gS), dim3(256), 0, stream, h, deg, bmu, bls, out_mu, out_ls, N);

    long long tE = (long long)E * 16;
    int gEd = (int)((tE + 255) / 256);
    hipLaunchKernelGGL(k_edges, dim3(gEd), dim3(256), 0, stream, src32, dst32, deg, h, out_mu, out_ls, E);
}

// Round 5
// 907.636 us; speedup vs baseline: 6.3840x; 6.3840x over previous
//
#include <hip/hip_runtime.h>
#include <hip/hip_bf16.h>

// GCN-VAE encoder: mu = S(xW_mu)+b_mu, logstd = S(xW_ls)+b_ls
// S = D^-1/2 (A+I) D^-1/2  (in-degree by dst, self-loops included)
//
// Rounds 3-5: replace f32-atomic scatter (6.4 GB HBM write-through, 5.4 ms)
// with CSR-by-dst build + per-node register-accumulated gather (writes out once).
//
// Pipeline:
//  1. k_detect : int64 vs int32 edge_index (data-driven, graph-capture safe)
//  2. k_zero   : cnt = cursor = 0
//  3. k_count  : cnt[dst]++ (int atomics into 400 KB L2-resident table)
//  4. k_scan   : rowptr = exclusive_scan(cnt)  (single-WG 1024-thread scan)
//  5. k_dinv   : dinv[i] = rsqrt(cnt[i]+1)     (+1 = self-loop)
//  6. k_fill   : esrc[rowptr[d] + cursor[d]++] = s   (CSR column indices)
//  7. k_gemm   : h[N][128] = x @ [W_mu | W_ls]  (fp32 VALU, LDS tiled)
//  8. k_out    : 1 wave/node: acc = dinv[i]^2*h[i] + sum_e dinv[s]dinv[i]*h[s];
//                out = acc + bias  (single coalesced write, no atomics)

#define IN_C 256
#define HC   128   // concatenated output channels (64 mu + 64 ls)
#define OC   64

// ---------------------------------------------------------------- detect
__global__ void k_detect(const void* ei, int n_scan, long long nn, int* flag) {
    __shared__ int bad;
    if (threadIdx.x == 0) bad = 0;
    __syncthreads();
    const long long* p = (const long long*)ei;
    for (int i = threadIdx.x; i < n_scan; i += blockDim.x) {
        long long v = p[i];
        if (v < 0 || v >= nn) bad = 1;   // benign race
    }
    __syncthreads();
    if (threadIdx.x == 0) *flag = bad;   // 1 => data is int32, 0 => int64
}

// ---------------------------------------------------------------- zero
__global__ __launch_bounds__(256) void k_zero(int* cnt, int* cursor, int n) {
    int i = blockIdx.x * 256 + threadIdx.x;
    if (i < n) { cnt[i] = 0; cursor[i] = 0; }
}

// ---------------------------------------------------------------- count in-degree
__global__ __launch_bounds__(256) void k_count(const void* ei, int* cnt, int E, const int* flag) {
    int e = blockIdx.x * 256 + threadIdx.x;
    if (e >= E) return;
    int d;
    if (*flag) d = ((const int*)ei)[(size_t)E + e];
    else       d = (int)((const long long*)ei)[(size_t)E + e];
    atomicAdd(&cnt[d], 1);
}

// ---------------------------------------------------------------- exclusive scan
// Single workgroup, 1024 threads, each owns a contiguous chunk of ~n/1024.
__global__ void k_scan(const int* __restrict__ cnt, int* __restrict__ rowptr, int n) {
    __shared__ int part[1024];
    const int tid = threadIdx.x;
    const int per = (n + 1023) >> 10;
    const int lo  = tid * per;
    const int hi  = min(lo + per, n);
    int s = 0;
    for (int i = lo; i < hi; ++i) s += cnt[i];
    part[tid] = s;
    __syncthreads();
    for (int off = 1; off < 1024; off <<= 1) {   // inclusive Hillis-Steele
        int v = (tid >= off) ? part[tid - off] : 0;
        __syncthreads();
        part[tid] += v;
        __syncthreads();
    }
    int run = (tid > 0) ? part[tid - 1] : 0;     // exclusive base for my chunk
    for (int i = lo; i < hi; ++i) { rowptr[i] = run; run += cnt[i]; }
    if (hi == n) rowptr[n] = run;                // total (benign multi-write)
}

// ---------------------------------------------------------------- dinv
__global__ __launch_bounds__(256) void k_dinv(const int* __restrict__ cnt, float* dinv, int n) {
    int i = blockIdx.x * 256 + threadIdx.x;
    if (i < n) dinv[i] = rsqrtf((float)(cnt[i] + 1));
}

// ---------------------------------------------------------------- CSR fill
__global__ __launch_bounds__(256) void k_fill(const void* ei, const int* __restrict__ rowptr,
                                              int* cursor, int* __restrict__ esrc,
                                              int E, const int* flag) {
    int e = blockIdx.x * 256 + threadIdx.x;
    if (e >= E) return;
    int s, d;
    if (*flag) {
        const int* p = (const int*)ei;
        s = p[e]; d = p[(size_t)E + e];
    } else {
        const long long* p = (const long long*)ei;
        s = (int)p[e]; d = (int)p[(size_t)E + e];
    }
    int pos = rowptr[d] + atomicAdd(&cursor[d], 1);
    esrc[pos] = s;
}

// ---------------------------------------------------------------- GEMM
// h[N][128] = x[N][256] @ [W_mu | W_ls][256][128]
#define BR 64
#define KC 32
__global__ __launch_bounds__(256) void k_gemm(const float* __restrict__ x,
                                              const float* __restrict__ Wmu,
                                              const float* __restrict__ Wls,
                                              float* __restrict__ hout, int nrows) {
    __shared__ float xs[BR][KC + 4];
    __shared__ float wsm[KC][HC];
    const int tid  = threadIdx.x;
    const int trow = tid >> 4;
    const int tcol = tid & 15;
    const int r0   = trow * 4;
    const int c0   = tcol * 4;
    const size_t rowbase = (size_t)blockIdx.x * BR;

    float acc[4][8];
    #pragma unroll
    for (int i = 0; i < 4; ++i)
        #pragma unroll
        for (int j = 0; j < 8; ++j) acc[i][j] = 0.0f;

    for (int kc = 0; kc < IN_C; kc += KC) {
        __syncthreads();
        {
            int lr = tid >> 3, lk = (tid & 7) * 4;
            #pragma unroll
            for (int half = 0; half < 2; ++half) {
                size_t gr = rowbase + lr + half * 32;
                float4 v = make_float4(0.f, 0.f, 0.f, 0.f);
                if (gr < (size_t)nrows)
                    v = *(const float4*)(x + gr * IN_C + kc + lk);
                *(float4*)&xs[lr + half * 32][lk] = v;
            }
        }
        #pragma unroll
        for (int i = 0; i < 4; ++i) {
            int q  = tid + 256 * i;
            int k  = q >> 5;
            int cq = (q & 31) * 4;
            const float* srcw = (cq < OC) ? (Wmu + (size_t)(kc + k) * OC + cq)
                                          : (Wls + (size_t)(kc + k) * OC + (cq - OC));
            *(float4*)&wsm[k][cq] = *(const float4*)srcw;
        }
        __syncthreads();

        #pragma unroll 8
        for (int k = 0; k < KC; ++k) {
            float4 w0 = *(const float4*)&wsm[k][c0];
            float4 w1 = *(const float4*)&wsm[k][c0 + OC];
            float xv[4];
            #pragma unroll
            for (int i = 0; i < 4; ++i) xv[i] = xs[r0 + i][k];
            #pragma unroll
            for (int i = 0; i < 4; ++i) {
                acc[i][0] += xv[i] * w0.x; acc[i][1] += xv[i] * w0.y;
                acc[i][2] += xv[i] * w0.z; acc[i][3] += xv[i] * w0.w;
                acc[i][4] += xv[i] * w1.x; acc[i][5] += xv[i] * w1.y;
                acc[i][6] += xv[i] * w1.z; acc[i][7] += xv[i] * w1.w;
            }
        }
    }
    #pragma unroll
    for (int i = 0; i < 4; ++i) {
        size_t gr = rowbase + r0 + i;
        if (gr < (size_t)nrows) {
            *(float4*)(hout + gr * HC + c0)      = make_float4(acc[i][0], acc[i][1], acc[i][2], acc[i][3]);
            *(float4*)(hout + gr * HC + OC + c0) = make_float4(acc[i][4], acc[i][5], acc[i][6], acc[i][7]);
        }
    }
}

// ---------------------------------------------------------------- per-node gather
// One wave (64 lanes) per node; lane owns channels 2*lane, 2*lane+1 (float2).
// Lanes 0..31 -> mu channels 0..63, lanes 32..63 -> logstd channels 0..63.
// 8-deep gather unroll: ~16 independent 8B loads in flight per lane
// (mean degree = E/N = 32, so the unrolled loop does most of the work).
__global__ __launch_bounds__(256) void k_out(const float* __restrict__ h,
                                             const int* __restrict__ rowptr,
                                             const int* __restrict__ esrc,
                                             const float* __restrict__ dinv,
                                             const float* __restrict__ bmu,
                                             const float* __restrict__ bls,
                                             float* __restrict__ out_mu,
                                             float* __restrict__ out_ls, int n) {
    int node = blockIdx.x * 4 + (threadIdx.x >> 6);
    if (node >= n) return;
    int lane = threadIdx.x & 63;
    const float2* __restrict__ h2 = (const float2*)h;

    float di = dinv[node];
    float2 self = h2[(size_t)node * 64 + lane];
    float w  = di * di;
    float ax = self.x * w, ay = self.y * w;

    int k   = rowptr[node];
    int end = rowptr[node + 1];

    for (; k + 7 < end; k += 8) {
        int   s[8];
        float nm[8];
        float2 v[8];
        #pragma unroll
        for (int u = 0; u < 8; ++u) s[u] = esrc[k + u];
        #pragma unroll
        for (int u = 0; u < 8; ++u) nm[u] = dinv[s[u]] * di;
        #pragma unroll
        for (int u = 0; u < 8; ++u) v[u] = h2[(size_t)s[u] * 64 + lane];
        #pragma unroll
        for (int u = 0; u < 8; ++u) { ax += v[u].x * nm[u]; ay += v[u].y * nm[u]; }
    }
    for (; k < end; ++k) {
        int s0 = esrc[k];
        float n0 = dinv[s0] * di;
        float2 v0 = h2[(size_t)s0 * 64 + lane];
        ax += v0.x * n0;
        ay += v0.y * n0;
    }

    if (lane < 32) {
        float2 b = ((const float2*)bmu)[lane];
        ((float2*)out_mu)[(size_t)node * 32 + lane] = make_float2(ax + b.x, ay + b.y);
    } else {
        float2 b = ((const float2*)bls)[lane - 32];
        ((float2*)out_ls)[(size_t)node * 32 + (lane - 32)] = make_float2(ax + b.x, ay + b.y);
    }
}

// ---------------------------------------------------------------- launch
extern "C" void kernel_launch(void* const* d_in, const int* in_sizes, int n_in,
                              void* d_out, int out_size, void* d_ws, size_t ws_size,
                              hipStream_t stream) {
    const float* x   = (const float*)d_in[0];
    const void*  ei  = d_in[1];
    const float* Wmu = (const float*)d_in[2];
    const float* bmu = (const float*)d_in[3];
    const float* Wls = (const float*)d_in[4];
    const float* bls = (const float*)d_in[5];

    const int N = in_sizes[0] / IN_C;
    const int E = in_sizes[1] / 2;

    float* out_mu = (float*)d_out;
    float* out_ls = (float*)d_out + (size_t)N * OC;

    // workspace layout (256B aligned)
    char* w = (char*)d_ws;
    auto align256 = [](size_t v) { return (v + 255) & ~(size_t)255; };
    int*   flag   = (int*)w;                  size_t off = 256;
    int*   cnt    = (int*)(w + off);          off += align256((size_t)N * 4);
    int*   cursor = (int*)(w + off);          off += align256((size_t)N * 4);
    float* dinv   = (float*)(w + off);        off += align256((size_t)N * 4);
    int*   rowptr = (int*)(w + off);          off += align256((size_t)(N + 1) * 4);
    int*   esrc   = (int*)(w + off);          off += align256((size_t)E * 4);
    float* h      = (float*)(w + off);        off += align256((size_t)N * HC * 4);

    int n_scan = E < 4096 ? E : 4096;
    hipLaunchKernelGGL(k_detect, dim3(1), dim3(256), 0, stream, ei, n_scan, (long long)N, flag);

    int gN = (N + 255) / 256;
    hipLaunchKernelGGL(k_zero, dim3(gN), dim3(256), 0, stream, cnt, cursor, N);

    int gE = (E + 255) / 256;
    hipLaunchKernelGGL(k_count, dim3(gE), dim3(256), 0, stream, ei, cnt, E, flag);

    hipLaunchKernelGGL(k_scan, dim3(1), dim3(1024), 0, stream, cnt, rowptr, N);
    hipLaunchKernelGGL(k_dinv, dim3(gN), dim3(256), 0, stream, cnt, dinv, N);
    hipLaunchKernelGGL(k_fill, dim3(gE), dim3(256), 0, stream, ei, rowptr, cursor, esrc, E, flag);

    int gG = (N + BR - 1) / BR;
    hipLaunchKernelGGL(k_gemm, dim3(gG), dim3(256), 0, stream, x, Wmu, Wls, h, N);

    int gO = (N + 3) / 4;
    hipLaunchKernelGGL(k_out, dim3(gO), dim3(256), 0, stream, h, rowptr, esrc, dinv, bmu, bls, out_mu, out_ls, N);
}